// Round 1
// baseline (477.385 us; speedup 1.0000x reference)
//
#include <hip/hip_runtime.h>
#include <hip/hip_bf16.h>

typedef __bf16 bf16x8 __attribute__((ext_vector_type(8)));
typedef float  f32x4  __attribute__((ext_vector_type(4)));

#define EDGES_TOTAL 1000000
#define TILES (EDGES_TOTAL / 32)   // 31250 wave-tiles of 32 edges

__device__ __forceinline__ bf16x8 load_cvt8(const float* __restrict__ p) {
    f32x4 a = *(const f32x4*)p;
    f32x4 b = *(const f32x4*)(p + 4);
    bf16x8 r;
    r[0] = (__bf16)a[0]; r[1] = (__bf16)a[1]; r[2] = (__bf16)a[2]; r[3] = (__bf16)a[3];
    r[4] = (__bf16)b[0]; r[5] = (__bf16)b[1]; r[6] = (__bf16)b[2]; r[7] = (__bf16)b[3];
    return r;
}

__global__ __launch_bounds__(256, 2) void sampleall_fused(
    const float* __restrict__ emb, const float* __restrict__ rel,
    const float* __restrict__ tokeys, const float* __restrict__ toqueries,
    const int* __restrict__ si, const int* __restrict__ pi, const int* __restrict__ oi,
    float* __restrict__ out)
{
    // W_k, W_q as bf16 in LDS, 64 KiB total. Within each 256B row, the
    // sixteen 16B granules are XOR-swizzled by (row&7) -> conflict-free
    // ds_read_b128 for the A-fragments (row stride 256B would otherwise
    // put all 16 fragment rows in the same bank quad).
    __shared__ __align__(16) __bf16 ldsW[2][128 * 128];

    const int tid = threadIdx.x;
    #pragma unroll
    for (int it = 0; it < 16; ++it) {
        int gidx = tid + it * 256;        // 0..4095 : 2 mats x 128 rows x 16 chunks
        int m    = gidx >> 11;
        int rm   = gidx & 2047;
        int row  = rm >> 4;
        int ch   = rm & 15;
        const float* src = (m ? toqueries : tokeys) + row * 128 + ch * 8;
        bf16x8 b = load_cvt8(src);
        int byteoff = row * 256 + ((ch * 16) ^ ((row & 7) << 4));
        *(bf16x8*)((char*)(&ldsW[m][0]) + byteoff) = b;
    }
    __syncthreads();

    const int lane = tid & 63;
    const int wid  = tid >> 6;
    const int c    = lane & 15;    // edge slot within half (and W fragment row)
    const int g    = lane >> 4;    // k-group
    const int xm   = (c & 7) << 4; // LDS swizzle mask for this lane's W rows
    const char* wkbase = (const char*)(&ldsW[0][0]) + c * 256;
    const char* wqbase = (const char*)(&ldsW[1][0]) + c * 256;

    const int wtotal = (int)gridDim.x * 4;
    for (int tile = (int)blockIdx.x * 4 + wid; tile < TILES; tile += wtotal) {
        const int e0 = tile * 32;
        const int sA = si[e0 + c], sB = si[e0 + 16 + c];
        const int oA = oi[e0 + c], oB = oi[e0 + 16 + c];
        const int pA = pi[e0 + c], pB = pi[e0 + 16 + c];
        const float* ps0 = emb + (size_t)sA * 128 + g * 8;
        const float* ps1 = emb + (size_t)sB * 128 + g * 8;
        const float* po0 = emb + (size_t)oA * 128 + g * 8;
        const float* po1 = emb + (size_t)oB * 128 + g * 8;

        f32x4 accK0[8], accK1[8], accQ0[8], accQ1[8];
        #pragma unroll
        for (int t = 0; t < 8; ++t) {
            accK0[t] = (f32x4){0.f, 0.f, 0.f, 0.f};
            accK1[t] = (f32x4){0.f, 0.f, 0.f, 0.f};
            accQ0[t] = (f32x4){0.f, 0.f, 0.f, 0.f};
            accQ1[t] = (f32x4){0.f, 0.f, 0.f, 0.f};
        }

        #pragma unroll
        for (int j0 = 0; j0 < 4; ++j0) {
            // B-fragments: 8 contiguous k-elements of the gathered rows (f32 -> bf16)
            bf16x8 bs0 = load_cvt8(ps0 + j0 * 32);
            bf16x8 bs1 = load_cvt8(ps1 + j0 * 32);
            bf16x8 bo0 = load_cvt8(po0 + j0 * 32);
            bf16x8 bo1 = load_cvt8(po1 + j0 * 32);
            const int offj = ((j0 * 64 + g * 16) ^ xm);   // swizzled within-row byte offset
            #pragma unroll
            for (int t = 0; t < 8; ++t) {
                bf16x8 aK = *(const bf16x8*)(wkbase + t * 4096 + offj);
                accK0[t] = __builtin_amdgcn_mfma_f32_16x16x32_bf16(aK, bs0, accK0[t], 0, 0, 0);
                accK1[t] = __builtin_amdgcn_mfma_f32_16x16x32_bf16(aK, bs1, accK1[t], 0, 0, 0);
                bf16x8 aQ = *(const bf16x8*)(wqbase + t * 4096 + offj);
                accQ0[t] = __builtin_amdgcn_mfma_f32_16x16x32_bf16(aQ, bo0, accQ0[t], 0, 0, 0);
                accQ1[t] = __builtin_amdgcn_mfma_f32_16x16x32_bf16(aQ, bo1, accQ1[t], 0, 0, 0);
            }
        }

        // Epilogue: lane (g,c) holds semb/qemb features i = t*16 + g*4 + r of its edge.
        float d0 = 0.f, d1 = 0.f;
        const float* relA = rel + (size_t)pA * 128 + g * 4;
        const float* relB = rel + (size_t)pB * 128 + g * 4;
        #pragma unroll
        for (int t = 0; t < 8; ++t) {
            f32x4 rA = *(const f32x4*)(relA + t * 16);
            f32x4 rB = *(const f32x4*)(relB + t * 16);
            #pragma unroll
            for (int r = 0; r < 4; ++r) {
                d0 += accK0[t][r] * accQ0[t][r] * rA[r];
                d1 += accK1[t][r] * accQ1[t][r] * rB[r];
            }
        }
        d0 += __shfl_xor(d0, 16); d0 += __shfl_xor(d0, 32);
        d1 += __shfl_xor(d1, 16); d1 += __shfl_xor(d1, 32);
        if (lane < 32) {
            const float inv_s = 0.08838834764831845f;  // 1/sqrt(128)
            out[e0 + lane] = (lane < 16 ? d0 : d1) * inv_s;
        }
    }
}

extern "C" void kernel_launch(void* const* d_in, const int* in_sizes, int n_in,
                              void* d_out, int out_size, void* d_ws, size_t ws_size,
                              hipStream_t stream)
{
    const float* emb = (const float*)d_in[0];
    const float* rel = (const float*)d_in[1];
    const float* tk  = (const float*)d_in[2];
    const float* tq  = (const float*)d_in[3];
    const int*   si  = (const int*)d_in[4];
    const int*   pi  = (const int*)d_in[5];
    const int*   oi  = (const int*)d_in[6];
    float* out = (float*)d_out;
    // 512 blocks = 2 resident blocks/CU on 256 CUs (64 KiB LDS each), grid-stride
    // over 31250 wave-tiles so W staging is amortized ~15x per block.
    sampleall_fused<<<dim3(512), dim3(256), 0, stream>>>(emb, rel, tk, tq, si, pi, oi, out);
}